// Round 3
// baseline (381.659 us; speedup 1.0000x reference)
//
#include <hip/hip_runtime.h>
#include <hip/hip_bf16.h>

#define HID 128

// Inputs: float32 (indices int32). Output: FLOAT32 (reference returns f32;
// round-2 bf16 write left half the f32 output buffer zero -> stub-level err).

// ---------------------------------------------------------------------------
// Kernel 1: per-node g_phi MLP -> gsq[n] = g(v_n, a_n)^2   (float, workspace)
// One block (128 threads) per node; thread j owns hidden unit j.
// ---------------------------------------------------------------------------
__global__ __launch_bounds__(HID) void node_g_kernel(
    const float* __restrict__ v,
    const float* __restrict__ a,
    const float* __restrict__ g0_w, const float* __restrict__ g0_b,
    const float* __restrict__ g1_w, const float* __restrict__ g1_b,
    const float* __restrict__ g2_w, const float* __restrict__ g2_b,
    float* __restrict__ gsq)
{
    const int node = blockIdx.x;
    const int j = threadIdx.x;

    __shared__ float h0[HID];
    __shared__ float red[HID];

    const float x0 = v[node];
    const float x1 = a[2 * node];
    const float x2 = a[2 * node + 1];

    float t = g0_b[j];
    t += x0 * g0_w[0 * HID + j];
    t += x1 * g0_w[1 * HID + j];
    t += x2 * g0_w[2 * HID + j];
    h0[j] = tanhf(t);
    __syncthreads();

    float acc = g1_b[j];
#pragma unroll 8
    for (int k = 0; k < HID; ++k) {
        acc += h0[k] * g1_w[k * HID + j];
    }
    const float h1 = tanhf(acc);

    red[j] = h1 * g2_w[j];
    __syncthreads();
#pragma unroll
    for (int s = HID / 2; s > 0; s >>= 1) {
        if (j < s) red[j] += red[j + s];
        __syncthreads();
    }
    if (j == 0) {
        const float g = red[0] + g2_b[0];
        gsq[node] = g * g;
    }
}

// ---------------------------------------------------------------------------
// Kernel 2: edge scatter  msg[dst[e]] += W[e] * gsq[src[e]]
// ---------------------------------------------------------------------------
__global__ __launch_bounds__(256) void edge_kernel(
    const int* __restrict__ src,
    const int* __restrict__ dst,
    const float* __restrict__ W,
    const float* __restrict__ gsq,
    float* __restrict__ msg,
    int E)
{
    const int e = blockIdx.x * blockDim.x + threadIdx.x;
    if (e < E) {
        atomicAdd(&msg[dst[e]], W[e] * gsq[src[e]]);
    }
}

// ---------------------------------------------------------------------------
// Kernel 3: per-node f_theta MLP -> dudt (f32 out)
// ---------------------------------------------------------------------------
__global__ __launch_bounds__(HID) void node_f_kernel(
    const float* __restrict__ v,
    const float* __restrict__ a,
    const float* __restrict__ msg,
    const float* __restrict__ exc,
    const float* __restrict__ f0_w, const float* __restrict__ f0_b,
    const float* __restrict__ f1_w, const float* __restrict__ f1_b,
    const float* __restrict__ f2_w, const float* __restrict__ f2_b,
    float* __restrict__ out)
{
    const int node = blockIdx.x;
    const int j = threadIdx.x;

    __shared__ float h0[HID];
    __shared__ float red[HID];

    const float x0 = v[node];
    const float x1 = a[2 * node];
    const float x2 = a[2 * node + 1];
    const float x3 = msg[node];
    const float x4 = exc[node];

    float t = f0_b[j];
    t += x0 * f0_w[0 * HID + j];
    t += x1 * f0_w[1 * HID + j];
    t += x2 * f0_w[2 * HID + j];
    t += x3 * f0_w[3 * HID + j];
    t += x4 * f0_w[4 * HID + j];
    h0[j] = tanhf(t);
    __syncthreads();

    float acc = f1_b[j];
#pragma unroll 8
    for (int k = 0; k < HID; ++k) {
        acc += h0[k] * f1_w[k * HID + j];
    }
    const float h1 = tanhf(acc);

    red[j] = h1 * f2_w[j];
    __syncthreads();
#pragma unroll
    for (int s = HID / 2; s > 0; s >>= 1) {
        if (j < s) red[j] += red[j + s];
        __syncthreads();
    }
    if (j == 0) {
        out[node] = red[0] + f2_b[0];
    }
}

extern "C" void kernel_launch(void* const* d_in, const int* in_sizes, int n_in,
                              void* d_out, int out_size, void* d_ws, size_t ws_size,
                              hipStream_t stream)
{
    const float* v    = (const float*)d_in[0];
    const float* exc  = (const float*)d_in[1];
    const int*   esrc = (const int*)d_in[2];
    const int*   edst = (const int*)d_in[3];
    const float* a    = (const float*)d_in[4];
    const float* W    = (const float*)d_in[5];
    const float* g0_w = (const float*)d_in[6];
    const float* g0_b = (const float*)d_in[7];
    const float* g1_w = (const float*)d_in[8];
    const float* g1_b = (const float*)d_in[9];
    const float* g2_w = (const float*)d_in[10];
    const float* g2_b = (const float*)d_in[11];
    const float* f0_w = (const float*)d_in[12];
    const float* f0_b = (const float*)d_in[13];
    const float* f1_w = (const float*)d_in[14];
    const float* f1_b = (const float*)d_in[15];
    const float* f2_w = (const float*)d_in[16];
    const float* f2_b = (const float*)d_in[17];

    const int N = in_sizes[0];   // N_NEURONS = 50000
    const int E = in_sizes[2];   // N_EDGES   = 1600000

    float* gsq = (float*)d_ws;       // N floats
    float* msg = gsq + N;            // N floats

    // msg must be zeroed every call (d_ws is re-poisoned before each launch)
    hipMemsetAsync(msg, 0, (size_t)N * sizeof(float), stream);

    node_g_kernel<<<N, HID, 0, stream>>>(v, a, g0_w, g0_b, g1_w, g1_b, g2_w, g2_b, gsq);

    edge_kernel<<<(E + 255) / 256, 256, 0, stream>>>(esrc, edst, W, gsq, msg, E);

    node_f_kernel<<<N, HID, 0, stream>>>(v, a, msg, exc,
                                         f0_w, f0_b, f1_w, f1_b, f2_w, f2_b,
                                         (float*)d_out);
}

// Round 4
// 277.253 us; speedup vs baseline: 1.3766x; 1.3766x over previous
//
#include <hip/hip_runtime.h>

#define HID 128
#define NB  16    // nodes per block (50000 % 16 == 0 -> 3125 full blocks)
#define NT  4     // nodes per thread  (n-tile)
#define JT  4     // hidden units per thread (j-tile); 32 j-threads * 4 = 128

// Inputs: float32 (indices int32). Output: float32.
//
// Layer-1 (128x128) is the hot loop. Round-3 profile: 1 node/block re-read
// 64 KB of w1 per block -> 3.2 GB L2 stream = 28 TB/s ~ L2 ceiling, VALUBusy
// only 36%. Fix: 16 nodes/block + 4x4 register tile -> w1 traffic /16 and
// 16 FMAs per 8 loads in the inner loop.

__device__ __forceinline__ float4 ld4(const float* p) { return *(const float4*)p; }

// ---------------------------------------------------------------------------
// node g_phi: gsq[n] = (MLP3(v,a))^2 ; also zeroes msg[] (edge_kernel runs
// strictly after this kernel, so no extra memset dispatch is needed).
// ---------------------------------------------------------------------------
__global__ __launch_bounds__(128) void node_g_kernel(
    const float* __restrict__ v, const float* __restrict__ a,
    const float* __restrict__ g0_w, const float* __restrict__ g0_b,
    const float* __restrict__ g1_w, const float* __restrict__ g1_b,
    const float* __restrict__ g2_w, const float* __restrict__ g2_b,
    float* __restrict__ gsq, float* __restrict__ msg, int N)
{
    const int tid  = threadIdx.x;
    const int base = blockIdx.x * NB;

    if (tid < NB) {
        const int node = base + tid;
        if (node < N) msg[node] = 0.0f;
    }

    __shared__ float h0[NB][HID];

    // ---- layer 0: thread tid owns unit j'=tid for all NB nodes ----
    {
        const float w00 = g0_w[0 * HID + tid];
        const float w01 = g0_w[1 * HID + tid];
        const float w02 = g0_w[2 * HID + tid];
        const float b0  = g0_b[tid];
#pragma unroll
        for (int n = 0; n < NB; ++n) {
            int node = base + n; if (node >= N) node = N - 1;   // clamp (no tail at N=50000)
            const float x0 = v[node];                            // uniform -> s_load
            const float x1 = a[2 * node];
            const float x2 = a[2 * node + 1];
            h0[n][tid] = tanhf(b0 + x0 * w00 + x1 * w01 + x2 * w02);
        }
    }
    __syncthreads();

    // ---- layer 1: 4x4 register tile ----
    const int jj = tid & 31;        // 32 j-threads
    const int nn = tid >> 5;        // 4 n-threads (contiguous 32-lane groups)
    const int j0 = jj * JT;
    const int n0 = nn * NT;

    float4 acc[NT];
    {
        const float4 b1 = ld4(&g1_b[j0]);
#pragma unroll
        for (int n = 0; n < NT; ++n) acc[n] = b1;
    }
    for (int k = 0; k < HID; k += 4) {
        float4 wv0 = ld4(&g1_w[(k + 0) * HID + j0]);
        float4 wv1 = ld4(&g1_w[(k + 1) * HID + j0]);
        float4 wv2 = ld4(&g1_w[(k + 2) * HID + j0]);
        float4 wv3 = ld4(&g1_w[(k + 3) * HID + j0]);
        float4 hv[NT];
#pragma unroll
        for (int n = 0; n < NT; ++n) hv[n] = ld4(&h0[n0 + n][k]);
#pragma unroll
        for (int n = 0; n < NT; ++n) {
            acc[n].x += hv[n].x * wv0.x + hv[n].y * wv1.x + hv[n].z * wv2.x + hv[n].w * wv3.x;
            acc[n].y += hv[n].x * wv0.y + hv[n].y * wv1.y + hv[n].z * wv2.y + hv[n].w * wv3.y;
            acc[n].z += hv[n].x * wv0.z + hv[n].y * wv1.z + hv[n].z * wv2.z + hv[n].w * wv3.z;
            acc[n].w += hv[n].x * wv0.w + hv[n].y * wv1.w + hv[n].z * wv2.w + hv[n].w * wv3.w;
        }
    }

    // ---- layer 2 + epilogue: reduce over j (32 jj-lanes per nn-group) ----
    const float4 w2v = ld4(&g2_w[j0]);
    const float  b2  = g2_b[0];
#pragma unroll
    for (int n = 0; n < NT; ++n) {
        float p = tanhf(acc[n].x) * w2v.x + tanhf(acc[n].y) * w2v.y
                + tanhf(acc[n].z) * w2v.z + tanhf(acc[n].w) * w2v.w;
        p += __shfl_down(p, 16);
        p += __shfl_down(p, 8);
        p += __shfl_down(p, 4);
        p += __shfl_down(p, 2);
        p += __shfl_down(p, 1);
        if (jj == 0) {
            const int node = base + n0 + n;
            if (node < N) { const float g = p + b2; gsq[node] = g * g; }
        }
    }
}

// ---------------------------------------------------------------------------
// edge scatter: msg[dst[e]] += W[e] * gsq[src[e]]   (x4 vectorized)
// ---------------------------------------------------------------------------
__global__ __launch_bounds__(256) void edge_kernel(
    const int* __restrict__ src, const int* __restrict__ dst,
    const float* __restrict__ W, const float* __restrict__ gsq,
    float* __restrict__ msg, int E)
{
    int e = (blockIdx.x * 256 + threadIdx.x) * 4;
    if (e + 3 < E) {
        const int4   s4 = *(const int4*)&src[e];
        const int4   d4 = *(const int4*)&dst[e];
        const float4 w4 = *(const float4*)&W[e];
        atomicAdd(&msg[d4.x], w4.x * gsq[s4.x]);
        atomicAdd(&msg[d4.y], w4.y * gsq[s4.y]);
        atomicAdd(&msg[d4.z], w4.z * gsq[s4.z]);
        atomicAdd(&msg[d4.w], w4.w * gsq[s4.w]);
    } else {
        for (; e < E; ++e) atomicAdd(&msg[dst[e]], W[e] * gsq[src[e]]);
    }
}

// ---------------------------------------------------------------------------
// node f_theta: out[n] = MLP3(v, a, msg, excitation)
// ---------------------------------------------------------------------------
__global__ __launch_bounds__(128) void node_f_kernel(
    const float* __restrict__ v, const float* __restrict__ a,
    const float* __restrict__ msg, const float* __restrict__ exc,
    const float* __restrict__ f0_w, const float* __restrict__ f0_b,
    const float* __restrict__ f1_w, const float* __restrict__ f1_b,
    const float* __restrict__ f2_w, const float* __restrict__ f2_b,
    float* __restrict__ out, int N)
{
    const int tid  = threadIdx.x;
    const int base = blockIdx.x * NB;

    __shared__ float h0[NB][HID];

    // ---- layer 0 ----
    {
        const float w00 = f0_w[0 * HID + tid];
        const float w01 = f0_w[1 * HID + tid];
        const float w02 = f0_w[2 * HID + tid];
        const float w03 = f0_w[3 * HID + tid];
        const float w04 = f0_w[4 * HID + tid];
        const float b0  = f0_b[tid];
#pragma unroll
        for (int n = 0; n < NB; ++n) {
            int node = base + n; if (node >= N) node = N - 1;
            const float x0 = v[node];
            const float x1 = a[2 * node];
            const float x2 = a[2 * node + 1];
            const float x3 = msg[node];
            const float x4 = exc[node];
            h0[n][tid] = tanhf(b0 + x0 * w00 + x1 * w01 + x2 * w02 + x3 * w03 + x4 * w04);
        }
    }
    __syncthreads();

    // ---- layer 1: 4x4 register tile ----
    const int jj = tid & 31;
    const int nn = tid >> 5;
    const int j0 = jj * JT;
    const int n0 = nn * NT;

    float4 acc[NT];
    {
        const float4 b1 = ld4(&f1_b[j0]);
#pragma unroll
        for (int n = 0; n < NT; ++n) acc[n] = b1;
    }
    for (int k = 0; k < HID; k += 4) {
        float4 wv0 = ld4(&f1_w[(k + 0) * HID + j0]);
        float4 wv1 = ld4(&f1_w[(k + 1) * HID + j0]);
        float4 wv2 = ld4(&f1_w[(k + 2) * HID + j0]);
        float4 wv3 = ld4(&f1_w[(k + 3) * HID + j0]);
        float4 hv[NT];
#pragma unroll
        for (int n = 0; n < NT; ++n) hv[n] = ld4(&h0[n0 + n][k]);
#pragma unroll
        for (int n = 0; n < NT; ++n) {
            acc[n].x += hv[n].x * wv0.x + hv[n].y * wv1.x + hv[n].z * wv2.x + hv[n].w * wv3.x;
            acc[n].y += hv[n].x * wv0.y + hv[n].y * wv1.y + hv[n].z * wv2.y + hv[n].w * wv3.y;
            acc[n].z += hv[n].x * wv0.z + hv[n].y * wv1.z + hv[n].z * wv2.z + hv[n].w * wv3.z;
            acc[n].w += hv[n].x * wv0.w + hv[n].y * wv1.w + hv[n].z * wv2.w + hv[n].w * wv3.w;
        }
    }

    // ---- layer 2 + write ----
    const float4 w2v = ld4(&f2_w[j0]);
    const float  b2  = f2_b[0];
#pragma unroll
    for (int n = 0; n < NT; ++n) {
        float p = tanhf(acc[n].x) * w2v.x + tanhf(acc[n].y) * w2v.y
                + tanhf(acc[n].z) * w2v.z + tanhf(acc[n].w) * w2v.w;
        p += __shfl_down(p, 16);
        p += __shfl_down(p, 8);
        p += __shfl_down(p, 4);
        p += __shfl_down(p, 2);
        p += __shfl_down(p, 1);
        if (jj == 0) {
            const int node = base + n0 + n;
            if (node < N) out[node] = p + b2;
        }
    }
}

extern "C" void kernel_launch(void* const* d_in, const int* in_sizes, int n_in,
                              void* d_out, int out_size, void* d_ws, size_t ws_size,
                              hipStream_t stream)
{
    const float* v    = (const float*)d_in[0];
    const float* exc  = (const float*)d_in[1];
    const int*   esrc = (const int*)d_in[2];
    const int*   edst = (const int*)d_in[3];
    const float* a    = (const float*)d_in[4];
    const float* W    = (const float*)d_in[5];
    const float* g0_w = (const float*)d_in[6];
    const float* g0_b = (const float*)d_in[7];
    const float* g1_w = (const float*)d_in[8];
    const float* g1_b = (const float*)d_in[9];
    const float* g2_w = (const float*)d_in[10];
    const float* g2_b = (const float*)d_in[11];
    const float* f0_w = (const float*)d_in[12];
    const float* f0_b = (const float*)d_in[13];
    const float* f1_w = (const float*)d_in[14];
    const float* f1_b = (const float*)d_in[15];
    const float* f2_w = (const float*)d_in[16];
    const float* f2_b = (const float*)d_in[17];

    const int N = in_sizes[0];   // 50000
    const int E = in_sizes[2];   // 1600000

    float* gsq = (float*)d_ws;   // N floats
    float* msg = gsq + N;        // N floats (zeroed inside node_g_kernel)

    const int nblocks = (N + NB - 1) / NB;

    node_g_kernel<<<nblocks, 128, 0, stream>>>(v, a, g0_w, g0_b, g1_w, g1_b,
                                               g2_w, g2_b, gsq, msg, N);

    edge_kernel<<<(E / 4 + 255) / 256, 256, 0, stream>>>(esrc, edst, W, gsq, msg, E);

    node_f_kernel<<<nblocks, 128, 0, stream>>>(v, a, msg, exc,
                                               f0_w, f0_b, f1_w, f1_b, f2_w, f2_b,
                                               (float*)d_out, N);
}

// Round 5
// 266.857 us; speedup vs baseline: 1.4302x; 1.0390x over previous
//
#include <hip/hip_runtime.h>

#define HID 128
#define NPB 64      // nodes per block (64 lanes = 64 nodes)
#define THREADS 256 // 4 waves; wave q owns j-tile [32q, 32q+32)

// Structure (round-5): nodes-on-lanes. Weight reads are wave-uniform ->
// scalar (SGPR) loads through K$; inner loop = 1 ds_read_b32 + 32 v_fmac
// (SGPR operand) per k. h0 stored transposed h0T[k][n] so lane n reads
// consecutive addresses (conflict-free). Edge scatter: 8 msg replicas to cut
// same-cache-line atomic RMW contention (round-4: 512 RMW/line, VALUBusy 0.4%).

__global__ __launch_bounds__(THREADS) void node_g_kernel(
    const float* __restrict__ v, const float* __restrict__ a,
    const float* __restrict__ g0_w, const float* __restrict__ g0_b,
    const float* __restrict__ g1_w, const float* __restrict__ g1_b,
    const float* __restrict__ g2_w, const float* __restrict__ g2_b,
    float* __restrict__ gsq, float* __restrict__ rep, int R, int N)
{
    // zero the R msg replicas (edge_kernel runs strictly after this kernel)
    {
        const int gid = blockIdx.x * THREADS + threadIdx.x;
        const int tot = R * N;
        for (int i = gid; i < tot; i += gridDim.x * THREADS) rep[i] = 0.0f;
    }

    const int lane = threadIdx.x & 63;
    const int q    = __builtin_amdgcn_readfirstlane(threadIdx.x >> 6); // wave id 0..3
    const int j0   = q * 32;
    const int base = blockIdx.x * NPB;

    __shared__ float h0T[HID * NPB];   // [k][n] -> 32 KB
    __shared__ float red[4][NPB];

    // ---- layer 0: this thread's node = base+lane; compute its j-tile ----
    {
        int node = base + lane; if (node >= N) node = N - 1;
        const float x0 = v[node];
        const float x1 = a[2 * node];
        const float x2 = a[2 * node + 1];
#pragma unroll
        for (int jj = 0; jj < 32; ++jj) {
            const int j = j0 + jj;                       // wave-uniform
            const float t = g0_b[j] + x0 * g0_w[0 * HID + j]
                                    + x1 * g0_w[1 * HID + j]
                                    + x2 * g0_w[2 * HID + j];
            h0T[j * NPB + lane] = tanhf(t);
        }
    }
    __syncthreads();

    // ---- layer 1: acc[jj] for j-tile, k streamed; weights via SGPR ----
    float acc[32];
#pragma unroll
    for (int jj = 0; jj < 32; ++jj) acc[jj] = g1_b[j0 + jj];

    float hcur = h0T[lane];
    for (int k = 0; k < HID; ++k) {
        const int kn = (k + 1 < HID) ? (k + 1) : k;
        const float hnext = h0T[kn * NPB + lane];        // prefetch next k
        const float* __restrict__ wrow = &g1_w[k * HID + j0]; // wave-uniform
#pragma unroll
        for (int jj = 0; jj < 32; ++jj) acc[jj] += wrow[jj] * hcur;
        hcur = hnext;
    }

    // ---- layer 2 partial + cross-wave reduce ----
    float p = 0.0f;
#pragma unroll
    for (int jj = 0; jj < 32; ++jj) p += g2_w[j0 + jj] * tanhf(acc[jj]);
    red[q][lane] = p;
    __syncthreads();
    if (q == 0) {
        const int node = base + lane;
        if (node < N) {
            const float g = red[0][lane] + red[1][lane] + red[2][lane]
                          + red[3][lane] + g2_b[0];
            gsq[node] = g * g;
        }
    }
}

// ---------------------------------------------------------------------------
// edge scatter into replica (blockIdx & (R-1)) to cut same-line contention
// ---------------------------------------------------------------------------
__global__ __launch_bounds__(256) void edge_kernel(
    const int* __restrict__ src, const int* __restrict__ dst,
    const float* __restrict__ W, const float* __restrict__ gsq,
    float* __restrict__ rep, int R, int N, int E)
{
    float* __restrict__ m = rep + (size_t)(blockIdx.x & (R - 1)) * N;
    int e = (blockIdx.x * 256 + threadIdx.x) * 4;
    if (e + 3 < E) {
        const int4   s4 = *(const int4*)&src[e];
        const int4   d4 = *(const int4*)&dst[e];
        const float4 w4 = *(const float4*)&W[e];
        atomicAdd(&m[d4.x], w4.x * gsq[s4.x]);
        atomicAdd(&m[d4.y], w4.y * gsq[s4.y]);
        atomicAdd(&m[d4.z], w4.z * gsq[s4.z]);
        atomicAdd(&m[d4.w], w4.w * gsq[s4.w]);
    } else {
        for (; e < E; ++e) atomicAdd(&m[dst[e]], W[e] * gsq[src[e]]);
    }
}

__global__ __launch_bounds__(THREADS) void node_f_kernel(
    const float* __restrict__ v, const float* __restrict__ a,
    const float* __restrict__ rep, const float* __restrict__ exc,
    const float* __restrict__ f0_w, const float* __restrict__ f0_b,
    const float* __restrict__ f1_w, const float* __restrict__ f1_b,
    const float* __restrict__ f2_w, const float* __restrict__ f2_b,
    float* __restrict__ out, int R, int N)
{
    const int lane = threadIdx.x & 63;
    const int q    = __builtin_amdgcn_readfirstlane(threadIdx.x >> 6);
    const int j0   = q * 32;
    const int base = blockIdx.x * NPB;

    __shared__ float h0T[HID * NPB];
    __shared__ float red[4][NPB];

    // ---- layer 0 ----
    {
        int node = base + lane; if (node >= N) node = N - 1;
        const float x0 = v[node];
        const float x1 = a[2 * node];
        const float x2 = a[2 * node + 1];
        float x3 = 0.0f;
        for (int r = 0; r < R; ++r) x3 += rep[(size_t)r * N + node];
        const float x4 = exc[node];
#pragma unroll
        for (int jj = 0; jj < 32; ++jj) {
            const int j = j0 + jj;
            const float t = f0_b[j] + x0 * f0_w[0 * HID + j]
                                    + x1 * f0_w[1 * HID + j]
                                    + x2 * f0_w[2 * HID + j]
                                    + x3 * f0_w[3 * HID + j]
                                    + x4 * f0_w[4 * HID + j];
            h0T[j * NPB + lane] = tanhf(t);
        }
    }
    __syncthreads();

    // ---- layer 1 ----
    float acc[32];
#pragma unroll
    for (int jj = 0; jj < 32; ++jj) acc[jj] = f1_b[j0 + jj];

    float hcur = h0T[lane];
    for (int k = 0; k < HID; ++k) {
        const int kn = (k + 1 < HID) ? (k + 1) : k;
        const float hnext = h0T[kn * NPB + lane];
        const float* __restrict__ wrow = &f1_w[k * HID + j0];
#pragma unroll
        for (int jj = 0; jj < 32; ++jj) acc[jj] += wrow[jj] * hcur;
        hcur = hnext;
    }

    // ---- layer 2 + write ----
    float p = 0.0f;
#pragma unroll
    for (int jj = 0; jj < 32; ++jj) p += f2_w[j0 + jj] * tanhf(acc[jj]);
    red[q][lane] = p;
    __syncthreads();
    if (q == 0) {
        const int node = base + lane;
        if (node < N) {
            out[node] = red[0][lane] + red[1][lane] + red[2][lane]
                      + red[3][lane] + f2_b[0];
        }
    }
}

extern "C" void kernel_launch(void* const* d_in, const int* in_sizes, int n_in,
                              void* d_out, int out_size, void* d_ws, size_t ws_size,
                              hipStream_t stream)
{
    const float* v    = (const float*)d_in[0];
    const float* exc  = (const float*)d_in[1];
    const int*   esrc = (const int*)d_in[2];
    const int*   edst = (const int*)d_in[3];
    const float* a    = (const float*)d_in[4];
    const float* W    = (const float*)d_in[5];
    const float* g0_w = (const float*)d_in[6];
    const float* g0_b = (const float*)d_in[7];
    const float* g1_w = (const float*)d_in[8];
    const float* g1_b = (const float*)d_in[9];
    const float* g2_w = (const float*)d_in[10];
    const float* g2_b = (const float*)d_in[11];
    const float* f0_w = (const float*)d_in[12];
    const float* f0_b = (const float*)d_in[13];
    const float* f1_w = (const float*)d_in[14];
    const float* f1_b = (const float*)d_in[15];
    const float* f2_w = (const float*)d_in[16];
    const float* f2_b = (const float*)d_in[17];

    const int N = in_sizes[0];   // 50000
    const int E = in_sizes[2];   // 1600000

    // replica count: largest power of two <= 8 that fits the workspace
    int R = 8;
    while (R > 1 && (size_t)(1 + R) * (size_t)N * sizeof(float) > ws_size) R >>= 1;

    float* gsq = (float*)d_ws;   // N floats
    float* rep = gsq + N;        // R*N floats (zeroed inside node_g_kernel)

    const int nblocks = (N + NPB - 1) / NPB;   // 782

    node_g_kernel<<<nblocks, THREADS, 0, stream>>>(v, a, g0_w, g0_b, g1_w, g1_b,
                                                   g2_w, g2_b, gsq, rep, R, N);

    edge_kernel<<<(E / 4 + 255) / 256, 256, 0, stream>>>(esrc, edst, W, gsq,
                                                         rep, R, N, E);

    node_f_kernel<<<nblocks, THREADS, 0, stream>>>(v, a, rep, exc,
                                                   f0_w, f0_b, f1_w, f1_b, f2_w, f2_b,
                                                   (float*)d_out, R, N);
}

// Round 6
// 162.852 us; speedup vs baseline: 2.3436x; 1.6387x over previous
//
#include <hip/hip_runtime.h>
#include <hip/hip_bf16.h>

#define HID   128
#define NPB   64      // nodes per node-kernel block
#define PITCH 136     // h0 LDS row pitch (bf16 elems): 128 + 8 pad
#define CH0   32768   // edge-binning chunk-0 size (128 KB LDS)

typedef float f32x4  __attribute__((ext_vector_type(4)));
typedef short bf16x8 __attribute__((ext_vector_type(8)));

__device__ __forceinline__ float fast_tanh(float x) {
    // tanh(x) = 1 - 2/(e^{2x}+1); saturates correctly at +-inf, NaN-free
    const float e = __expf(2.0f * x);
    return 1.0f - 2.0f / (e + 1.0f);
}

__device__ __forceinline__ short f2bf(float x) {
    union { __hip_bfloat16 h; short s; } u;
    u.h = __float2bfloat16(x);
    return u.s;
}

// ---------------------------------------------------------------------------
// node g_phi: gsq[n] = (MLP3(v,a))^2.  Layer-1 = MFMA bf16, layers 0/2 fp32.
// Wave wq owns j-tiles {2wq, 2wq+1}; W1 A-fragments persist in VGPRs.
// ---------------------------------------------------------------------------
__global__ __launch_bounds__(256) void node_g_kernel(
    const float* __restrict__ v, const float* __restrict__ a,
    const float* __restrict__ g0_w, const float* __restrict__ g0_b,
    const float* __restrict__ g1_w, const float* __restrict__ g1_b,
    const float* __restrict__ g2_w, const float* __restrict__ g2_b,
    float* __restrict__ gsq, int N)
{
    const int t    = threadIdx.x;
    const int lane = t & 63;
    const int wq   = t >> 6;
    const int base = blockIdx.x * NPB;
    const int m    = lane & 15;   // A-row / D-col / B-col within tile
    const int kg   = lane >> 4;   // k-group (8 k's each)

    __shared__ __align__(16) __hip_bfloat16 h0bf[NPB * PITCH];
    __shared__ float xv[NPB];
    __shared__ float xa[2 * NPB];
    __shared__ float red[4][4][16];   // [wave][ntile][n]

    // ---- stage node inputs (coalesced) ----
    if (t < NPB) {
        int node = base + t; if (node >= N) node = N - 1;
        xv[t] = v[node];
    } else if (t >= 128) {
        int idx = 2 * base + (t - 128);
        const int lim = 2 * N - 1; if (idx > lim) idx = lim;
        xa[t - 128] = a[idx];
    }

    // ---- persistent W1 A-fragments: A[m][k] = w1[k][j0+m] ----
    bf16x8 afrag[2][4];
#pragma unroll
    for (int jt = 0; jt < 2; ++jt) {
        const int j = (2 * wq + jt) * 16 + m;
#pragma unroll
        for (int s = 0; s < 4; ++s) {
            const int k0 = 32 * s + 8 * kg;
            bf16x8 f;
#pragma unroll
            for (int e = 0; e < 8; ++e)
                f[e] = f2bf(g1_w[(k0 + e) * HID + j]);
            afrag[jt][s] = f;
        }
    }
    // per-lane bias/w2 at D positions j = (2wq+jt)*16 + 4*kg + r
    float b1v[2][4], w2v[2][4];
#pragma unroll
    for (int jt = 0; jt < 2; ++jt)
#pragma unroll
        for (int r = 0; r < 4; ++r) {
            const int j = (2 * wq + jt) * 16 + 4 * kg + r;
            b1v[jt][r] = g1_b[j];
            w2v[jt][r] = g2_w[j];
        }
    __syncthreads();

    // ---- layer 0: j on lanes (t&127), nodes looped; bf16 into LDS ----
    {
        const int j    = t & 127;
        const int half = t >> 7;
        const float w00 = g0_w[0 * HID + j];
        const float w01 = g0_w[1 * HID + j];
        const float w02 = g0_w[2 * HID + j];
        const float b0  = g0_b[j];
#pragma unroll 4
        for (int i = 0; i < 32; ++i) {
            const int nn = half * 32 + i;
            const float x0 = xv[nn];
            const float x1 = xa[2 * nn];
            const float x2 = xa[2 * nn + 1];
            h0bf[nn * PITCH + j] =
                __float2bfloat16(fast_tanh(b0 + x0 * w00 + x1 * w01 + x2 * w02));
        }
    }
    __syncthreads();

    // ---- layer 1 (MFMA) + layer 2 per 16-node tile ----
#pragma unroll
    for (int nt = 0; nt < 4; ++nt) {
        const int n = nt * 16 + m;
        f32x4 acc0 = {0.f, 0.f, 0.f, 0.f};
        f32x4 acc1 = {0.f, 0.f, 0.f, 0.f};
#pragma unroll
        for (int s = 0; s < 4; ++s) {
            const bf16x8 b = *(const bf16x8*)&h0bf[n * PITCH + 32 * s + 8 * kg];
            acc0 = __builtin_amdgcn_mfma_f32_16x16x32_bf16(afrag[0][s], b, acc0, 0, 0, 0);
            acc1 = __builtin_amdgcn_mfma_f32_16x16x32_bf16(afrag[1][s], b, acc1, 0, 0, 0);
        }
        float p = 0.f;
#pragma unroll
        for (int r = 0; r < 4; ++r) {
            p += w2v[0][r] * fast_tanh(acc0[r] + b1v[0][r]);
            p += w2v[1][r] * fast_tanh(acc1[r] + b1v[1][r]);
        }
        p += __shfl_down(p, 32);
        p += __shfl_down(p, 16);
        if (lane < 16) red[wq][nt][lane] = p;
    }
    __syncthreads();

    if (t < NPB) {
        const int node = base + t;
        if (node < N) {
            const float g = red[0][t >> 4][t & 15] + red[1][t >> 4][t & 15]
                          + red[2][t >> 4][t & 15] + red[3][t >> 4][t & 15]
                          + g2_b[0];
            gsq[node] = g * g;
        }
    }
}

// ---------------------------------------------------------------------------
// edge scatter via LDS binning: grid = 2 chunks x B parts. Block (p, c) bins
// its edge slice's chunk-c messages into LDS, then flushes the WHOLE chunk
// range to partial[p] (unconditional -> no pre-zero needed). No global atomics.
// ---------------------------------------------------------------------------
__global__ __launch_bounds__(256) void edge_kernel(
    const int* __restrict__ src, const int* __restrict__ dst,
    const float* __restrict__ W, const float* __restrict__ gsq,
    float* __restrict__ partial, int B, int N, int E)
{
    __shared__ float loc[CH0];
    const int t = threadIdx.x;
    const int p = blockIdx.x >> 1;
    const int c = blockIdx.x & 1;

    const f32x4 z4 = {0.f, 0.f, 0.f, 0.f};
    for (int i = 4 * t; i < CH0; i += 1024) *(f32x4*)&loc[i] = z4;
    __syncthreads();

    int cnt = (E + B - 1) / B;
    cnt = (cnt + 3) & ~3;                  // keep slice starts 16B-aligned
    const int start = p * cnt;
    int end = start + cnt; if (end > E) end = E;
    const int coff = c << 15;              // c * CH0

    if (start < end) {
        const int nvec = (end - start) & ~3;
        for (int i = 4 * t; i < nvec; i += 1024) {
            const int e = start + i;
            const int4   s4 = *(const int4*)&src[e];
            const int4   d4 = *(const int4*)&dst[e];
            const float4 w4 = *(const float4*)&W[e];
            if ((d4.x >> 15) == c) atomicAdd(&loc[d4.x - coff], w4.x * gsq[s4.x]);
            if ((d4.y >> 15) == c) atomicAdd(&loc[d4.y - coff], w4.y * gsq[s4.y]);
            if ((d4.z >> 15) == c) atomicAdd(&loc[d4.z - coff], w4.z * gsq[s4.z]);
            if ((d4.w >> 15) == c) atomicAdd(&loc[d4.w - coff], w4.w * gsq[s4.w]);
        }
        for (int e = start + nvec + t; e < end; e += 256) {
            const int d = dst[e];
            if ((d >> 15) == c) atomicAdd(&loc[d - coff], W[e] * gsq[src[e]]);
        }
    }
    __syncthreads();

    const int chN = c ? (N - CH0) : CH0;
    float* __restrict__ dp = partial + (size_t)p * N + coff;
    const int chV = chN & ~3;
    for (int i = 4 * t; i < chV; i += 1024) *(f32x4*)&dp[i] = *(const f32x4*)&loc[i];
    for (int i = chV + t; i < chN; i += 256) dp[i] = loc[i];
}

// ---------------------------------------------------------------------------
// node f_theta: out[n] = MLP3(v, a, msg, excitation); msg = sum of B partials
// ---------------------------------------------------------------------------
__global__ __launch_bounds__(256) void node_f_kernel(
    const float* __restrict__ v, const float* __restrict__ a,
    const float* __restrict__ exc, const float* __restrict__ partial, int B,
    const float* __restrict__ f0_w, const float* __restrict__ f0_b,
    const float* __restrict__ f1_w, const float* __restrict__ f1_b,
    const float* __restrict__ f2_w, const float* __restrict__ f2_b,
    float* __restrict__ out, int N)
{
    const int t    = threadIdx.x;
    const int lane = t & 63;
    const int wq   = t >> 6;
    const int base = blockIdx.x * NPB;
    const int m    = lane & 15;
    const int kg   = lane >> 4;

    __shared__ __align__(16) __hip_bfloat16 h0bf[NPB * PITCH];
    __shared__ float xv[NPB];
    __shared__ float xe[NPB];
    __shared__ float xa[2 * NPB];
    __shared__ float xm4[4][NPB];
    __shared__ float red[4][4][16];

    // ---- stage node inputs ----
    if (t < NPB) {
        int node = base + t; if (node >= N) node = N - 1;
        xv[t] = v[node];
    } else if (t < 128) {
        int node = base + (t - 64); if (node >= N) node = N - 1;
        xe[t - 64] = exc[node];
    } else {
        int idx = 2 * base + (t - 128);
        const int lim = 2 * N - 1; if (idx > lim) idx = lim;
        xa[t - 128] = a[idx];
    }
    {   // msg partial-sum: group g sums parts [g*B/4, (g+1)*B/4)
        const int n16 = t & 63, grp = t >> 6;
        int node = base + n16; if (node >= N) node = N - 1;
        const int pb = B >> 2;
        float s = 0.f;
        for (int p = grp * pb; p < (grp + 1) * pb; ++p)
            s += partial[(size_t)p * N + node];
        xm4[grp][n16] = s;
    }

    // ---- persistent W1 fragments ----
    bf16x8 afrag[2][4];
#pragma unroll
    for (int jt = 0; jt < 2; ++jt) {
        const int j = (2 * wq + jt) * 16 + m;
#pragma unroll
        for (int s = 0; s < 4; ++s) {
            const int k0 = 32 * s + 8 * kg;
            bf16x8 f;
#pragma unroll
            for (int e = 0; e < 8; ++e)
                f[e] = f2bf(f1_w[(k0 + e) * HID + j]);
            afrag[jt][s] = f;
        }
    }
    float b1v[2][4], w2v[2][4];
#pragma unroll
    for (int jt = 0; jt < 2; ++jt)
#pragma unroll
        for (int r = 0; r < 4; ++r) {
            const int j = (2 * wq + jt) * 16 + 4 * kg + r;
            b1v[jt][r] = f1_b[j];
            w2v[jt][r] = f2_w[j];
        }
    __syncthreads();

    // ---- layer 0 (5 inputs) ----
    {
        const int j    = t & 127;
        const int half = t >> 7;
        const float w00 = f0_w[0 * HID + j];
        const float w01 = f0_w[1 * HID + j];
        const float w02 = f0_w[2 * HID + j];
        const float w03 = f0_w[3 * HID + j];
        const float w04 = f0_w[4 * HID + j];
        const float b0  = f0_b[j];
#pragma unroll 4
        for (int i = 0; i < 32; ++i) {
            const int nn = half * 32 + i;
            const float x0 = xv[nn];
            const float x1 = xa[2 * nn];
            const float x2 = xa[2 * nn + 1];
            const float x3 = (xm4[0][nn] + xm4[1][nn]) + (xm4[2][nn] + xm4[3][nn]);
            const float x4 = xe[nn];
            h0bf[nn * PITCH + j] = __float2bfloat16(
                fast_tanh(b0 + x0 * w00 + x1 * w01 + x2 * w02 + x3 * w03 + x4 * w04));
        }
    }
    __syncthreads();

    // ---- layer 1 (MFMA) + layer 2 ----
#pragma unroll
    for (int nt = 0; nt < 4; ++nt) {
        const int n = nt * 16 + m;
        f32x4 acc0 = {0.f, 0.f, 0.f, 0.f};
        f32x4 acc1 = {0.f, 0.f, 0.f, 0.f};
#pragma unroll
        for (int s = 0; s < 4; ++s) {
            const bf16x8 b = *(const bf16x8*)&h0bf[n * PITCH + 32 * s + 8 * kg];
            acc0 = __builtin_amdgcn_mfma_f32_16x16x32_bf16(afrag[0][s], b, acc0, 0, 0, 0);
            acc1 = __builtin_amdgcn_mfma_f32_16x16x32_bf16(afrag[1][s], b, acc1, 0, 0, 0);
        }
        float p = 0.f;
#pragma unroll
        for (int r = 0; r < 4; ++r) {
            p += w2v[0][r] * fast_tanh(acc0[r] + b1v[0][r]);
            p += w2v[1][r] * fast_tanh(acc1[r] + b1v[1][r]);
        }
        p += __shfl_down(p, 32);
        p += __shfl_down(p, 16);
        if (lane < 16) red[wq][nt][lane] = p;
    }
    __syncthreads();

    if (t < NPB) {
        const int node = base + t;
        if (node < N) {
            out[node] = red[0][t >> 4][t & 15] + red[1][t >> 4][t & 15]
                      + red[2][t >> 4][t & 15] + red[3][t >> 4][t & 15]
                      + f2_b[0];
        }
    }
}

extern "C" void kernel_launch(void* const* d_in, const int* in_sizes, int n_in,
                              void* d_out, int out_size, void* d_ws, size_t ws_size,
                              hipStream_t stream)
{
    const float* v    = (const float*)d_in[0];
    const float* exc  = (const float*)d_in[1];
    const int*   esrc = (const int*)d_in[2];
    const int*   edst = (const int*)d_in[3];
    const float* a    = (const float*)d_in[4];
    const float* W    = (const float*)d_in[5];
    const float* g0_w = (const float*)d_in[6];
    const float* g0_b = (const float*)d_in[7];
    const float* g1_w = (const float*)d_in[8];
    const float* g1_b = (const float*)d_in[9];
    const float* g2_w = (const float*)d_in[10];
    const float* g2_b = (const float*)d_in[11];
    const float* f0_w = (const float*)d_in[12];
    const float* f0_b = (const float*)d_in[13];
    const float* f1_w = (const float*)d_in[14];
    const float* f1_b = (const float*)d_in[15];
    const float* f2_w = (const float*)d_in[16];
    const float* f2_b = (const float*)d_in[17];

    const int N = in_sizes[0];   // 50000
    const int E = in_sizes[2];   // 1600000

    // parts: largest power-of-two B with (1+B)*N floats fitting the workspace
    int B = 128;
    while (B > 4 && (size_t)(1 + B) * (size_t)N * sizeof(float) > ws_size) B >>= 1;

    float* gsq     = (float*)d_ws;   // N floats
    float* partial = gsq + N;        // B*N floats (fully overwritten by flush)

    const int nblocks = (N + NPB - 1) / NPB;   // 782

    node_g_kernel<<<nblocks, 256, 0, stream>>>(v, a, g0_w, g0_b, g1_w, g1_b,
                                               g2_w, g2_b, gsq, N);

    edge_kernel<<<2 * B, 256, 0, stream>>>(esrc, edst, W, gsq, partial, B, N, E);

    node_f_kernel<<<nblocks, 256, 0, stream>>>(v, a, exc, partial, B,
                                               f0_w, f0_b, f1_w, f1_b, f2_w, f2_b,
                                               (float*)d_out, N);
}

// Round 8
// 157.052 us; speedup vs baseline: 2.4301x; 1.0369x over previous
//
#include <hip/hip_runtime.h>
#include <hip/hip_bf16.h>

#define HID   128
#define NPB   64      // nodes per node-kernel block
#define PITCH 136     // h0 LDS row pitch (bf16 elems): 128 + 8 pad
#define CH0   32768   // edge-binning chunk-0 size (128 KB LDS); assumes N<=65536

#define FRAGN 16384   // shorts per repacked W1: 8 j16 x 4 s x 64 lanes x 8 bf16

typedef float f32x4  __attribute__((ext_vector_type(4)));
typedef short bf16x8 __attribute__((ext_vector_type(8)));

__device__ __forceinline__ float fast_tanh(float x) {
    const float e = __expf(2.0f * x);
    return 1.0f - 2.0f / (e + 1.0f);
}

__device__ __forceinline__ short f2bf(float x) {
    union { __hip_bfloat16 h; short s; } u;
    u.h = __float2bfloat16(x);
    return u.s;
}

// ---------------------------------------------------------------------------
// prep: repack W1 into lane-fragment order (bf16) + pack b1/w2 per lane.
//   frag[((j16*4+s)*64 + lane)*8 + e] = bf16( w1[(32s+8*(lane>>4)+e)*HID + j16*16+(lane&15)] )
//   bw[(j16*64+lane)*8 + r]   = b1[j16*16 + 4*(lane>>4) + r]
//   bw[(j16*64+lane)*8 + 4+r] = w2[j16*16 + 4*(lane>>4) + r]
// ROUND-7 BUG FIX: frag is 2048 entries x 8 shorts = 16384 shorts per matrix
// (was laid out as 8192 -> gfrag overran ffrag, ffrag raced gbw -> NaN).
// ---------------------------------------------------------------------------
__global__ __launch_bounds__(256) void prep_kernel(
    const float* __restrict__ g1_w, const float* __restrict__ g1_b, const float* __restrict__ g2_w,
    const float* __restrict__ f1_w, const float* __restrict__ f1_b, const float* __restrict__ f2_w,
    short* __restrict__ gfrag, short* __restrict__ ffrag,
    float* __restrict__ gbw, float* __restrict__ fbw)
{
    const int id  = blockIdx.x * 256 + threadIdx.x;   // 0..5119
    const int mat = (id >= 2560);
    const int r   = id - (mat ? 2560 : 0);
    const float* __restrict__ w1 = mat ? f1_w : g1_w;
    const float* __restrict__ b1 = mat ? f1_b : g1_b;
    const float* __restrict__ w2 = mat ? f2_w : g2_w;
    short* __restrict__ frag = mat ? ffrag : gfrag;
    float* __restrict__ bw   = mat ? fbw   : gbw;

    if (r < 2048) {
        const int j16  = r >> 8;
        const int s    = (r >> 6) & 3;
        const int lane = r & 63;
        const int m = lane & 15, kg = lane >> 4;
        const int j  = j16 * 16 + m;
        const int k0 = 32 * s + 8 * kg;
        bf16x8 f;
#pragma unroll
        for (int e = 0; e < 8; ++e) f[e] = f2bf(w1[(k0 + e) * HID + j]);
        *(bf16x8*)&frag[r * 8] = f;
    } else if (r < 2560) {
        const int q = r - 2048;            // 0..511
        const int j16 = q >> 6, lane = q & 63, kg = lane >> 4;
#pragma unroll
        for (int rr = 0; rr < 4; ++rr) {
            bw[q * 8 + rr]     = b1[j16 * 16 + 4 * kg + rr];
            bw[q * 8 + 4 + rr] = w2[j16 * 16 + 4 * kg + rr];
        }
    }
}

// ---------------------------------------------------------------------------
// node g_phi: gsq[n] = (MLP3(v,a))^2.  Layer-1 = MFMA bf16, layers 0/2 fp32.
// ---------------------------------------------------------------------------
__global__ __launch_bounds__(256) void node_g_kernel(
    const float* __restrict__ v, const float* __restrict__ a,
    const float* __restrict__ g0_w, const float* __restrict__ g0_b,
    const short* __restrict__ gfrag, const float* __restrict__ gbw,
    const float* __restrict__ g2_b,
    float* __restrict__ gsq, int N)
{
    const int t    = threadIdx.x;
    const int lane = t & 63;
    const int wq   = t >> 6;
    const int base = blockIdx.x * NPB;
    const int m    = lane & 15;
    const int kg   = lane >> 4;

    __shared__ __align__(16) __hip_bfloat16 h0bf[NPB * PITCH];
    __shared__ float xv[NPB];
    __shared__ float xa[2 * NPB];
    __shared__ float red[4][4][16];

    if (t < NPB) {
        int node = base + t; if (node >= N) node = N - 1;
        xv[t] = v[node];
    } else if (t >= 128) {
        int idx = 2 * base + (t - 128);
        const int lim = 2 * N - 1; if (idx > lim) idx = lim;
        xa[t - 128] = a[idx];
    }

    // ---- persistent W1 fragments: one coalesced 16B load each ----
    bf16x8 afrag[2][4];
    float b1v[2][4], w2v[2][4];
    const bf16x8* __restrict__ fb = (const bf16x8*)gfrag;
#pragma unroll
    for (int jt = 0; jt < 2; ++jt) {
        const int j16 = 2 * wq + jt;
#pragma unroll
        for (int s = 0; s < 4; ++s)
            afrag[jt][s] = fb[(j16 * 4 + s) * 64 + lane];
        const f32x4 bv = *(const f32x4*)&gbw[(j16 * 64 + lane) * 8];
        const f32x4 wv = *(const f32x4*)&gbw[(j16 * 64 + lane) * 8 + 4];
#pragma unroll
        for (int r = 0; r < 4; ++r) { b1v[jt][r] = bv[r]; w2v[jt][r] = wv[r]; }
    }
    __syncthreads();

    // ---- layer 0 ----
    {
        const int j    = t & 127;
        const int half = t >> 7;
        const float w00 = g0_w[0 * HID + j];
        const float w01 = g0_w[1 * HID + j];
        const float w02 = g0_w[2 * HID + j];
        const float b0  = g0_b[j];
#pragma unroll 4
        for (int i = 0; i < 32; ++i) {
            const int nn = half * 32 + i;
            h0bf[nn * PITCH + j] = __float2bfloat16(
                fast_tanh(b0 + xv[nn] * w00 + xa[2 * nn] * w01 + xa[2 * nn + 1] * w02));
        }
    }
    __syncthreads();

    // ---- layer 1 (MFMA) + layer 2 ----
#pragma unroll
    for (int nt = 0; nt < 4; ++nt) {
        const int n = nt * 16 + m;
        f32x4 acc0 = {0.f, 0.f, 0.f, 0.f};
        f32x4 acc1 = {0.f, 0.f, 0.f, 0.f};
#pragma unroll
        for (int s = 0; s < 4; ++s) {
            const bf16x8 b = *(const bf16x8*)&h0bf[n * PITCH + 32 * s + 8 * kg];
            acc0 = __builtin_amdgcn_mfma_f32_16x16x32_bf16(afrag[0][s], b, acc0, 0, 0, 0);
            acc1 = __builtin_amdgcn_mfma_f32_16x16x32_bf16(afrag[1][s], b, acc1, 0, 0, 0);
        }
        float p = 0.f;
#pragma unroll
        for (int r = 0; r < 4; ++r) {
            p += w2v[0][r] * fast_tanh(acc0[r] + b1v[0][r]);
            p += w2v[1][r] * fast_tanh(acc1[r] + b1v[1][r]);
        }
        p += __shfl_down(p, 32);
        p += __shfl_down(p, 16);
        if (lane < 16) red[wq][nt][lane] = p;
    }
    __syncthreads();

    if (t < NPB) {
        const int node = base + t;
        if (node < N) {
            const float g = red[0][t >> 4][t & 15] + red[1][t >> 4][t & 15]
                          + red[2][t >> 4][t & 15] + red[3][t >> 4][t & 15]
                          + g2_b[0];
            gsq[node] = g * g;
        }
    }
}

// ---------------------------------------------------------------------------
// edge scatter via LDS binning: grid = 2 chunks x B parts; no global atomics.
// ---------------------------------------------------------------------------
__global__ __launch_bounds__(256) void edge_kernel(
    const int* __restrict__ src, const int* __restrict__ dst,
    const float* __restrict__ W, const float* __restrict__ gsq,
    float* __restrict__ partial, int B, int N, int E)
{
    __shared__ float loc[CH0];
    const int t = threadIdx.x;
    const int p = blockIdx.x >> 1;
    const int c = blockIdx.x & 1;

    const f32x4 z4 = {0.f, 0.f, 0.f, 0.f};
    for (int i = 4 * t; i < CH0; i += 1024) *(f32x4*)&loc[i] = z4;
    __syncthreads();

    int cnt = (E + B - 1) / B;
    cnt = (cnt + 3) & ~3;
    const int start = p * cnt;
    int end = start + cnt; if (end > E) end = E;
    const int coff = c << 15;

    if (start < end) {
        const int nvec = (end - start) & ~3;
        for (int i = 4 * t; i < nvec; i += 1024) {
            const int e = start + i;
            const int4   s4 = *(const int4*)&src[e];
            const int4   d4 = *(const int4*)&dst[e];
            const float4 w4 = *(const float4*)&W[e];
            if ((d4.x >> 15) == c) atomicAdd(&loc[d4.x - coff], w4.x * gsq[s4.x]);
            if ((d4.y >> 15) == c) atomicAdd(&loc[d4.y - coff], w4.y * gsq[s4.y]);
            if ((d4.z >> 15) == c) atomicAdd(&loc[d4.z - coff], w4.z * gsq[s4.z]);
            if ((d4.w >> 15) == c) atomicAdd(&loc[d4.w - coff], w4.w * gsq[s4.w]);
        }
        for (int e = start + nvec + t; e < end; e += 256) {
            const int d = dst[e];
            if ((d >> 15) == c) atomicAdd(&loc[d - coff], W[e] * gsq[src[e]]);
        }
    }
    __syncthreads();

    int chN = c ? (N - CH0) : CH0; if (chN > CH0) chN = CH0;
    float* __restrict__ dp = partial + (size_t)p * N + coff;
    const int chV = chN & ~3;
    for (int i = 4 * t; i < chV; i += 1024) *(f32x4*)&dp[i] = *(const f32x4*)&loc[i];
    for (int i = chV + t; i < chN; i += 256) dp[i] = loc[i];
}

// ---------------------------------------------------------------------------
// node f_theta: out[n] = MLP3(v, a, msg, excitation); msg = sum of B partials
// ---------------------------------------------------------------------------
__global__ __launch_bounds__(256) void node_f_kernel(
    const float* __restrict__ v, const float* __restrict__ a,
    const float* __restrict__ exc, const float* __restrict__ partial, int B,
    const float* __restrict__ f0_w, const float* __restrict__ f0_b,
    const short* __restrict__ ffrag, const float* __restrict__ fbw,
    const float* __restrict__ f2_b,
    float* __restrict__ out, int N)
{
    const int t    = threadIdx.x;
    const int lane = t & 63;
    const int wq   = t >> 6;
    const int base = blockIdx.x * NPB;
    const int m    = lane & 15;
    const int kg   = lane >> 4;

    __shared__ __align__(16) __hip_bfloat16 h0bf[NPB * PITCH];
    __shared__ float xv[NPB];
    __shared__ float xe[NPB];
    __shared__ float xa[2 * NPB];
    __shared__ float xm4[4][NPB];
    __shared__ float red[4][4][16];

    if (t < NPB) {
        int node = base + t; if (node >= N) node = N - 1;
        xv[t] = v[node];
    } else if (t < 128) {
        int node = base + (t - 64); if (node >= N) node = N - 1;
        xe[t - 64] = exc[node];
    } else {
        int idx = 2 * base + (t - 128);
        const int lim = 2 * N - 1; if (idx > lim) idx = lim;
        xa[t - 128] = a[idx];
    }
    {
        const int n16 = t & 63, grp = t >> 6;
        int node = base + n16; if (node >= N) node = N - 1;
        const int pb = B >> 2;
        float s = 0.f;
        for (int p = grp * pb; p < (grp + 1) * pb; ++p)
            s += partial[(size_t)p * N + node];
        xm4[grp][n16] = s;
    }

    // ---- persistent W1 fragments (coalesced) ----
    bf16x8 afrag[2][4];
    float b1v[2][4], w2v[2][4];
    const bf16x8* __restrict__ fb = (const bf16x8*)ffrag;
#pragma unroll
    for (int jt = 0; jt < 2; ++jt) {
        const int j16 = 2 * wq + jt;
#pragma unroll
        for (int s = 0; s < 4; ++s)
            afrag[jt][s] = fb[(j16 * 4 + s) * 64 + lane];
        const f32x4 bv = *(const f32x4*)&fbw[(j16 * 64 + lane) * 8];
        const f32x4 wv = *(const f32x4*)&fbw[(j16 * 64 + lane) * 8 + 4];
#pragma unroll
        for (int r = 0; r < 4; ++r) { b1v[jt][r] = bv[r]; w2v[jt][r] = wv[r]; }
    }
    __syncthreads();

    // ---- layer 0 (5 inputs) ----
    {
        const int j    = t & 127;
        const int half = t >> 7;
        const float w00 = f0_w[0 * HID + j];
        const float w01 = f0_w[1 * HID + j];
        const float w02 = f0_w[2 * HID + j];
        const float w03 = f0_w[3 * HID + j];
        const float w04 = f0_w[4 * HID + j];
        const float b0  = f0_b[j];
#pragma unroll 4
        for (int i = 0; i < 32; ++i) {
            const int nn = half * 32 + i;
            const float x3 = (xm4[0][nn] + xm4[1][nn]) + (xm4[2][nn] + xm4[3][nn]);
            h0bf[nn * PITCH + j] = __float2bfloat16(
                fast_tanh(b0 + xv[nn] * w00 + xa[2 * nn] * w01 + xa[2 * nn + 1] * w02
                             + x3 * w03 + xe[nn] * w04));
        }
    }
    __syncthreads();

    // ---- layer 1 (MFMA) + layer 2 ----
#pragma unroll
    for (int nt = 0; nt < 4; ++nt) {
        const int n = nt * 16 + m;
        f32x4 acc0 = {0.f, 0.f, 0.f, 0.f};
        f32x4 acc1 = {0.f, 0.f, 0.f, 0.f};
#pragma unroll
        for (int s = 0; s < 4; ++s) {
            const bf16x8 b = *(const bf16x8*)&h0bf[n * PITCH + 32 * s + 8 * kg];
            acc0 = __builtin_amdgcn_mfma_f32_16x16x32_bf16(afrag[0][s], b, acc0, 0, 0, 0);
            acc1 = __builtin_amdgcn_mfma_f32_16x16x32_bf16(afrag[1][s], b, acc1, 0, 0, 0);
        }
        float p = 0.f;
#pragma unroll
        for (int r = 0; r < 4; ++r) {
            p += w2v[0][r] * fast_tanh(acc0[r] + b1v[0][r]);
            p += w2v[1][r] * fast_tanh(acc1[r] + b1v[1][r]);
        }
        p += __shfl_down(p, 32);
        p += __shfl_down(p, 16);
        if (lane < 16) red[wq][nt][lane] = p;
    }
    __syncthreads();

    if (t < NPB) {
        const int node = base + t;
        if (node < N) {
            out[node] = red[0][t >> 4][t & 15] + red[1][t >> 4][t & 15]
                      + red[2][t >> 4][t & 15] + red[3][t >> 4][t & 15]
                      + f2_b[0];
        }
    }
}

extern "C" void kernel_launch(void* const* d_in, const int* in_sizes, int n_in,
                              void* d_out, int out_size, void* d_ws, size_t ws_size,
                              hipStream_t stream)
{
    const float* v    = (const float*)d_in[0];
    const float* exc  = (const float*)d_in[1];
    const int*   esrc = (const int*)d_in[2];
    const int*   edst = (const int*)d_in[3];
    const float* a    = (const float*)d_in[4];
    const float* W    = (const float*)d_in[5];
    const float* g0_w = (const float*)d_in[6];
    const float* g0_b = (const float*)d_in[7];
    const float* g1_w = (const float*)d_in[8];
    const float* g1_b = (const float*)d_in[9];
    const float* g2_w = (const float*)d_in[10];
    const float* g2_b = (const float*)d_in[11];
    const float* f0_w = (const float*)d_in[12];
    const float* f0_b = (const float*)d_in[13];
    const float* f1_w = (const float*)d_in[14];
    const float* f1_b = (const float*)d_in[15];
    const float* f2_w = (const float*)d_in[16];
    const float* f2_b = (const float*)d_in[17];

    const int N = in_sizes[0];   // 50000
    const int E = in_sizes[2];   // 1600000

    int B = 128;
    while (B > 4 && (size_t)(1 + B) * (size_t)N * sizeof(float) + 131072 > ws_size) B >>= 1;

    float* gsq     = (float*)d_ws;          // N floats
    float* partial = gsq + N;               // B*N floats (fully overwritten)
    short* gfrag   = (short*)(partial + (size_t)B * N);  // FRAGN shorts (32 KB)
    short* ffrag   = gfrag + FRAGN;                       // FRAGN shorts (32 KB)
    float* gbw     = (float*)(ffrag + FRAGN);             // 4096 floats
    float* fbw     = gbw + 4096;                          // 4096 floats

    const int nblocks = (N + NPB - 1) / NPB;   // 782

    prep_kernel<<<20, 256, 0, stream>>>(g1_w, g1_b, g2_w, f1_w, f1_b, f2_w,
                                        gfrag, ffrag, gbw, fbw);

    node_g_kernel<<<nblocks, 256, 0, stream>>>(v, a, g0_w, g0_b,
                                               gfrag, gbw, g2_b, gsq, N);

    edge_kernel<<<2 * B, 256, 0, stream>>>(esrc, edst, W, gsq, partial, B, N, E);

    node_f_kernel<<<nblocks, 256, 0, stream>>>(v, a, exc, partial, B,
                                               f0_w, f0_b, ffrag, fbw, f2_b,
                                               (float*)d_out, N);
}